// Round 7
// baseline (644.484 us; speedup 1.0000x reference)
//
#include <hip/hip_runtime.h>

// MSTGCN block, MI355X.
//  R2: 256-thread k_fused blocks. R3: LDS staging of x/P1/P2. R4: packed weights (neutral).
//  R5: lane re-partition (c0=lane&15, tg=lane>>4): each lane owns 4 co x 4 t.
//      DS reads become 4-distinct-address (no pure broadcast), per-item DS ops
//      ~920 -> ~350 (diagnosed per-CU DS-pipe saturation). LN reduce uses only
//      xor 1/2/4/8. Phase-2 weight loads via VMEM, 2-deep software pipeline.
//  R6: no bench last round (broker timeout); audited resubmit of R5.

#define F_IN 32
#define TT   16
#define CCH  64
#define FTN  512   // F_IN*TT floats per (b,n)
#define WPB  4     // waves per block in k_fused
#define WSTR 1536  // per-wave LDS floats: staging 1536 / sg 64*24=1536 (overlay)

__global__ void k_edge1(const int* __restrict__ row, const int* __restrict__ col,
                        float* __restrict__ deg, int* __restrict__ cnt,
                        int* __restrict__ pos, int E) {
    int i = blockIdx.x * 256 + threadIdx.x;
    if (i < E) {
        atomicAdd(&deg[row[i]], 1.0f);
        pos[i] = atomicAdd(&cnt[col[i]], 1);
    }
}

__global__ void k_scan(const int* __restrict__ cnt, int* __restrict__ rowptr, int n) {
    __shared__ int sdata[1024];
    int tid = threadIdx.x;
    int run = 0;
    for (int base = 0; base < n; base += 1024) {
        int v = (base + tid < n) ? cnt[base + tid] : 0;
        sdata[tid] = v;
        __syncthreads();
        for (int off = 1; off < 1024; off <<= 1) {
            int add = (tid >= off) ? sdata[tid - off] : 0;
            __syncthreads();
            sdata[tid] += add;
            __syncthreads();
        }
        int incl  = sdata[tid];
        int total = sdata[1023];
        if (base + tid < n) rowptr[base + tid] = run + incl - v;
        run += total;
        __syncthreads();
    }
    if (tid == 0) rowptr[n] = run;
}

__global__ void k_fill(const int* __restrict__ row, const int* __restrict__ col,
                       const float* __restrict__ deg, const int* __restrict__ rowptr,
                       const int* __restrict__ pos, int* __restrict__ srcs,
                       float* __restrict__ wsort, int E) {
    int i = blockIdx.x * 256 + threadIdx.x;
    if (i < E) {
        int r = row[i], c = col[i];
        float dr = deg[r], dc = deg[c];
        float w = 0.0f;
        if (dr > 0.0f && dc > 0.0f) w = -(rsqrtf(dr) * rsqrtf(dc));
        int slot = rowptr[c] + pos[i];
        srcs[slot]  = r;
        wsort[slot] = w;
    }
}

// Gather prop: one block per destination node. 256 threads x float4 = full
// B*F*T row of one source per iteration. 4-edge unroll for MLP. No atomics.
__global__ void k_prop(const float* __restrict__ zin, float* __restrict__ zout,
                       const int* __restrict__ rowptr, const int* __restrict__ srcs,
                       const float* __restrict__ wsort, int N) {
    int n   = blockIdx.x;
    int tid = threadIdx.x;                 // 0..255
    int beg = rowptr[n], end = rowptr[n + 1];
    const size_t bstride = (size_t)N * FTN;
    const size_t eoff = (size_t)(tid >> 7) * bstride + (size_t)(tid & 127) * 4;

    float4 a = make_float4(0.f, 0.f, 0.f, 0.f);
    int j = beg;
    for (; j + 3 < end; j += 4) {
        int   s0 = srcs[j],  s1 = srcs[j + 1], s2 = srcs[j + 2], s3 = srcs[j + 3];
        float w0 = wsort[j], w1 = wsort[j + 1], w2 = wsort[j + 2], w3 = wsort[j + 3];
        float4 v0 = *reinterpret_cast<const float4*>(zin + (size_t)s0 * FTN + eoff);
        float4 v1 = *reinterpret_cast<const float4*>(zin + (size_t)s1 * FTN + eoff);
        float4 v2 = *reinterpret_cast<const float4*>(zin + (size_t)s2 * FTN + eoff);
        float4 v3 = *reinterpret_cast<const float4*>(zin + (size_t)s3 * FTN + eoff);
        a.x = fmaf(w0, v0.x, fmaf(w1, v1.x, fmaf(w2, v2.x, fmaf(w3, v3.x, a.x))));
        a.y = fmaf(w0, v0.y, fmaf(w1, v1.y, fmaf(w2, v2.y, fmaf(w3, v3.y, a.y))));
        a.z = fmaf(w0, v0.z, fmaf(w1, v1.z, fmaf(w2, v2.z, fmaf(w3, v3.z, a.z))));
        a.w = fmaf(w0, v0.w, fmaf(w1, v1.w, fmaf(w2, v2.w, fmaf(w3, v3.w, a.w))));
    }
    for (; j < end; ++j) {
        int   s0 = srcs[j];
        float w0 = wsort[j];
        float4 v0 = *reinterpret_cast<const float4*>(zin + (size_t)s0 * FTN + eoff);
        a.x = fmaf(w0, v0.x, a.x);
        a.y = fmaf(w0, v0.y, a.y);
        a.z = fmaf(w0, v0.z, a.z);
        a.w = fmaf(w0, v0.w, a.w);
    }
    *reinterpret_cast<float4*>(zout + (size_t)n * FTN + eoff) = a;
}

// Weight prep:
//   pW4[f*64 + co]           = { W0-W2, W1, 2*W2, resW }          (2048 float4)
//   pTg[ci*48 + dt*16 + c0]  = { tw[co=c0], tw[c0+16], tw[c0+32], tw[c0+48] } (3072 float4)
__global__ void k_prep(const float* __restrict__ cheb_W, const float* __restrict__ time_W,
                       const float* __restrict__ res_W,
                       float4* __restrict__ pW4, float4* __restrict__ pTg) {
    int i = blockIdx.x * 256 + threadIdx.x;
    if (i < F_IN * 64) {
        int f = i >> 6, o = i & 63;
        float w0 = cheb_W[(0 * F_IN + f) * 64 + o];
        float w1 = cheb_W[(1 * F_IN + f) * 64 + o];
        float w2 = cheb_W[(2 * F_IN + f) * 64 + o];
        pW4[i] = make_float4(w0 - w2, w1, 2.0f * w2, res_W[o * F_IN + f]);
    }
    if (i < 64 * 3 * 16) {
        int ci = i / 48, r = i % 48, dt = r >> 4, c0 = r & 15;
        pTg[i] = make_float4(time_W[((c0      ) * 64 + ci) * 3 + dt],
                             time_W[((c0 + 16) * 64 + ci) * 3 + dt],
                             time_W[((c0 + 32) * 64 + ci) * 3 + dt],
                             time_W[((c0 + 48) * 64 + ci) * 3 + dt]);
    }
}

// phase-1 inner: one packed weight load + 16 FMA-triples for co-slot kk
#define P1K(kk)                                                                              \
    { float4 wv = pW4[f * 64 + c0 + 16 * kk];                                                \
      acc[kk*4+0] = fmaf(wv.x, xv.x, fmaf(wv.y, av.x, fmaf(wv.z, bv.x, acc[kk*4+0])));       \
      acc[kk*4+1] = fmaf(wv.x, xv.y, fmaf(wv.y, av.y, fmaf(wv.z, bv.y, acc[kk*4+1])));       \
      acc[kk*4+2] = fmaf(wv.x, xv.z, fmaf(wv.y, av.z, fmaf(wv.z, bv.z, acc[kk*4+2])));       \
      acc[kk*4+3] = fmaf(wv.x, xv.w, fmaf(wv.y, av.w, fmaf(wv.z, bv.w, acc[kk*4+3])));       \
      res[kk*4+0] = fmaf(wv.w, xv.x, res[kk*4+0]);                                           \
      res[kk*4+1] = fmaf(wv.w, xv.y, res[kk*4+1]);                                           \
      res[kk*4+2] = fmaf(wv.w, xv.z, res[kk*4+2]);                                           \
      res[kk*4+3] = fmaf(wv.w, xv.w, res[kk*4+3]); }

// phase-2 inner: co-slot kk, weight components w0c/w1c/w2c, window sm1..s4v
#define P2K(kk, w0c, w1c, w2c)                                                               \
    acc[kk*4+0] = fmaf(w0c, sm1, fmaf(w1c, s0v, fmaf(w2c, s1v, acc[kk*4+0])));               \
    acc[kk*4+1] = fmaf(w0c, s0v, fmaf(w1c, s1v, fmaf(w2c, s2v, acc[kk*4+1])));               \
    acc[kk*4+2] = fmaf(w0c, s1v, fmaf(w1c, s2v, fmaf(w2c, s3v, acc[kk*4+2])));               \
    acc[kk*4+3] = fmaf(w0c, s2v, fmaf(w1c, s3v, fmaf(w2c, s4v, acc[kk*4+3])));

#define P2COMP(W0, W1, W2, R0, R1, R2)                                                       \
    { float sm1 = R0.w, s0v = R1.x, s1v = R1.y, s2v = R1.z, s3v = R1.w, s4v = R2.x;          \
      P2K(0, W0.x, W1.x, W2.x)  P2K(1, W0.y, W1.y, W2.y)                                     \
      P2K(2, W0.z, W1.z, W2.z)  P2K(3, W0.w, W1.w, W2.w) }

// Fused per-(b,n) kernel. 256 threads = 4 waves; each wave owns one item (b,n).
// lane = (c0 = lane&15, tg = lane>>4): 4 co-slots x 4 timesteps per lane.
__global__ __launch_bounds__(256, 4) void k_fused(
        const float* __restrict__ x, const float* __restrict__ P1, const float* __restrict__ P2,
        const float4* __restrict__ pW4, const float4* __restrict__ pTg,
        const float* __restrict__ cheb_b, const float* __restrict__ time_b,
        const float* __restrict__ res_b, const float* __restrict__ ln_g,
        const float* __restrict__ ln_b, float* __restrict__ out, int N) {
    __shared__ float smem[WPB * WSTR];
    int lane = threadIdx.x & 63;
    int wib  = threadIdx.x >> 6;
    int c0   = lane & 15;
    int tg   = lane >> 4;
    float*  st = smem + wib * WSTR;
    float4* s4 = reinterpret_cast<float4*>(st);   // staging: [0:128)=x, [128:256)=P1, [256:384)=P2

    // per-lane biases / LN params for its 4 co-slots (hoisted; item-independent)
    float chb[4], tb[4], rb[4], g[4], bb[4];
#pragma unroll
    for (int k = 0; k < 4; ++k) {
        chb[k] = cheb_b[c0 + 16 * k];
        tb[k]  = time_b[c0 + 16 * k];
        rb[k]  = res_b[c0 + 16 * k];
        g[k]   = ln_g[c0 + 16 * k];
        bb[k]  = ln_b[c0 + 16 * k];
    }

    int gw = blockIdx.x * WPB + wib;
    int nw = gridDim.x * WPB;
    int nitems = 2 * N;
    const size_t bstride = (size_t)N * FTN;

    for (int item = gw; item < nitems; item += nw) {
        int b = (item >= N) ? 1 : 0;
        int n = item - b * N;
        const float4* x4 = reinterpret_cast<const float4*>(x  + b * bstride + (size_t)n * FTN);
        const float4* a4 = reinterpret_cast<const float4*>(P1 + b * bstride + (size_t)n * FTN);
        const float4* b4 = reinterpret_cast<const float4*>(P2 + b * bstride + (size_t)n * FTN);

        // coalesced stage: 6 x (64 lanes x 16 B) = x,P1,P2 rows into LDS
        s4[lane]       = x4[lane];  s4[64 + lane]  = x4[64 + lane];
        s4[128 + lane] = a4[lane];  s4[192 + lane] = a4[64 + lane];
        s4[256 + lane] = b4[lane];  s4[320 + lane] = b4[64 + lane];

        float acc[16], res[16];
#pragma unroll
        for (int k = 0; k < 4; ++k)
#pragma unroll
            for (int j = 0; j < 4; ++j) { acc[k*4+j] = chb[k]; res[k*4+j] = rb[k]; }

        // phase 1: cheb einsum (3 mats) + residual 1x1. Per f: 3 DS reads
        // (4 distinct addrs: tg) + 4 packed VMEM weight loads + 64 FMA.
#pragma unroll 4
        for (int f = 0; f < F_IN; ++f) {
            float4 xv = s4[f * 4 + tg];
            float4 av = s4[128 + f * 4 + tg];
            float4 bv = s4[256 + f * 4 + tg];
            P1K(0) P1K(1) P1K(2) P1K(3)
        }

        // relu -> sg tile overlaying staging. Row ci: 24 floats; idx3 = t(-1),
        // idx4..19 = t0..15, idx20 = t16. Lane writes 4 b128 (its 4 co rows,
        // its 4-t chunk); halo zeros by tg==0 / tg==1 lanes.
#pragma unroll
        for (int k = 0; k < 4; ++k) {
            float4 sv = make_float4(fmaxf(acc[k*4+0], 0.f), fmaxf(acc[k*4+1], 0.f),
                                    fmaxf(acc[k*4+2], 0.f), fmaxf(acc[k*4+3], 0.f));
            *reinterpret_cast<float4*>(st + (c0 + 16 * k) * 24 + 4 + 4 * tg) = sv;
        }
        if (tg == 0) {
#pragma unroll
            for (int k = 0; k < 4; ++k) st[(c0 + 16 * k) * 24 + 3] = 0.f;
        } else if (tg == 1) {
#pragma unroll
            for (int k = 0; k < 4; ++k) st[(c0 + 16 * k) * 24 + 20] = 0.f;
        }

        // phase 2: temporal conv (kernel 3, pad 1). Per ci: 3 DS reads
        // (4 distinct addrs) + 3 packed VMEM weight loads + 48 FMA.
        // 2-deep software pipeline (A/B) to hide L2 weight latency.
#pragma unroll
        for (int k = 0; k < 4; ++k)
#pragma unroll
            for (int j = 0; j < 4; ++j) acc[k*4+j] = res[k*4+j] + tb[k];

        float4 wA0, wA1, wA2, rA0, rA1, rA2, wB0, wB1, wB2, rB0, rB1, rB2;
        {   // prologue: ci = 0
            wA0 = pTg[c0]; wA1 = pTg[16 + c0]; wA2 = pTg[32 + c0];
            const float4* sr = reinterpret_cast<const float4*>(st + 4 * tg);
            rA0 = sr[0]; rA1 = sr[1]; rA2 = sr[2];
        }
        for (int ci = 0; ci < 64; ci += 2) {
            {   // load B = ci+1
                int cn = ci + 1;
                wB0 = pTg[cn * 48 + c0]; wB1 = pTg[cn * 48 + 16 + c0]; wB2 = pTg[cn * 48 + 32 + c0];
                const float4* sr = reinterpret_cast<const float4*>(st + cn * 24 + 4 * tg);
                rB0 = sr[0]; rB1 = sr[1]; rB2 = sr[2];
            }
            P2COMP(wA0, wA1, wA2, rA0, rA1, rA2)
            if (ci + 2 < 64) {   // load A = ci+2
                int cn = ci + 2;
                wA0 = pTg[cn * 48 + c0]; wA1 = pTg[cn * 48 + 16 + c0]; wA2 = pTg[cn * 48 + 32 + c0];
                const float4* sr = reinterpret_cast<const float4*>(st + cn * 24 + 4 * tg);
                rA0 = sr[0]; rA1 = sr[1]; rA2 = sr[2];
            }
            P2COMP(wB0, wB1, wB2, rB0, rB1, rB2)
        }

        // relu + LayerNorm over co (4 in-lane slots x 16 lanes), xor 1/2/4/8 only
        float zz[16], s1[4] = {0.f, 0.f, 0.f, 0.f}, s2[4] = {0.f, 0.f, 0.f, 0.f};
#pragma unroll
        for (int k = 0; k < 4; ++k)
#pragma unroll
            for (int j = 0; j < 4; ++j) {
                float v = fmaxf(acc[k*4+j], 0.f);
                zz[k*4+j] = v;
                s1[j] += v;
                s2[j] = fmaf(v, v, s2[j]);
            }
#pragma unroll
        for (int off = 1; off <= 8; off <<= 1)
#pragma unroll
            for (int j = 0; j < 4; ++j) {
                s1[j] += __shfl_xor(s1[j], off);
                s2[j] += __shfl_xor(s2[j], off);
            }
        float mu[4], rinv[4];
#pragma unroll
        for (int j = 0; j < 4; ++j) {
            mu[j] = s1[j] * (1.0f / 64.0f);
            float var = s2[j] * (1.0f / 64.0f) - mu[j] * mu[j];
            rinv[j] = rsqrtf(var + 1e-5f);
        }
        // write out[item][co][t]: per k one b128 at t=4tg..4tg+3
        float* ob = out + (size_t)item * 1024;
#pragma unroll
        for (int k = 0; k < 4; ++k) {
            float4 o;
            o.x = (zz[k*4+0] - mu[0]) * rinv[0] * g[k] + bb[k];
            o.y = (zz[k*4+1] - mu[1]) * rinv[1] * g[k] + bb[k];
            o.z = (zz[k*4+2] - mu[2]) * rinv[2] * g[k] + bb[k];
            o.w = (zz[k*4+3] - mu[3]) * rinv[3] * g[k] + bb[k];
            *reinterpret_cast<float4*>(ob + (c0 + 16 * k) * 16 + 4 * tg) = o;
        }
    }
}

extern "C" void kernel_launch(void* const* d_in, const int* in_sizes, int n_in,
                              void* d_out, int out_size, void* d_ws, size_t ws_size,
                              hipStream_t stream) {
    const float* x      = (const float*)d_in[0];
    const int*   ei     = (const int*)d_in[1];
    const float* cheb_W = (const float*)d_in[2];
    const float* cheb_b = (const float*)d_in[3];
    const float* time_W = (const float*)d_in[4];
    const float* time_b = (const float*)d_in[5];
    const float* res_W  = (const float*)d_in[6];
    const float* res_b  = (const float*)d_in[7];
    const float* ln_g   = (const float*)d_in[8];
    const float* ln_b   = (const float*)d_in[9];
    float* out = (float*)d_out;

    const int N = in_sizes[0] / (2 * F_IN * TT);   // B=2
    const int E = in_sizes[1] / 2;
    const int* row = ei;
    const int* col = ei + E;

    // workspace carve-out (256B aligned)
    char* w = (char*)d_ws;
    size_t off = 0;
    auto carve = [&](size_t bytes) { off = (off + 255) & ~(size_t)255; size_t o = off; off += bytes; return o; };
    float*  deg    = (float*) (w + carve((size_t)N * 4));
    int*    cnt    = (int*)   (w + carve((size_t)N * 4));
    int*    rowptr = (int*)   (w + carve((size_t)(N + 1) * 4));
    int*    pos    = (int*)   (w + carve((size_t)E * 4));
    int*    srcs   = (int*)   (w + carve((size_t)E * 4));
    float*  wsort  = (float*) (w + carve((size_t)E * 4));
    float4* pW4    = (float4*)(w + carve((size_t)F_IN * 64 * 16));
    float4* pTg    = (float4*)(w + carve((size_t)64 * 3 * 16 * 16));
    float*  P1     = (float*) (w + carve((size_t)2 * N * FTN * 4));
    float*  P2     = (float*) (w + carve((size_t)2 * N * FTN * 4));
    (void)ws_size; (void)n_in; (void)out_size;

    hipMemsetAsync(deg, 0, (size_t)N * 4, stream);
    hipMemsetAsync(cnt, 0, (size_t)N * 4, stream);

    int eb = (E + 255) / 256;
    k_edge1<<<eb, 256, 0, stream>>>(row, col, deg, cnt, pos, E);
    k_scan<<<1, 1024, 0, stream>>>(cnt, rowptr, N);
    k_fill<<<eb, 256, 0, stream>>>(row, col, deg, rowptr, pos, srcs, wsort, E);
    k_prop<<<N, 256, 0, stream>>>(x,  P1, rowptr, srcs, wsort, N);
    k_prop<<<N, 256, 0, stream>>>(P1, P2, rowptr, srcs, wsort, N);
    k_prep<<<16, 256, 0, stream>>>(cheb_W, time_W, res_W, pW4, pTg);

    int items  = 2 * N;
    int blocks = (items + WPB - 1) / WPB;   // 4 waves/block, 1 item/wave
    k_fused<<<blocks, 64 * WPB, 0, stream>>>(x, P1, P2, pW4, pTg,
                                             cheb_b, time_b, res_b, ln_g, ln_b, out, N);
}

// Round 8
// 624.056 us; speedup vs baseline: 1.0327x; 1.0327x over previous
//
#include <hip/hip_runtime.h>

// MSTGCN block, MI355X.
//  R2: 256-thread k_fused blocks. R3: LDS staging of x/P1/P2. R4: packed weights.
//  R5: lane re-partition (c0=lane&15, tg=lane>>4): 4 co x 4 t per lane; DS reads
//      4-distinct-address, LN via xor 1/2/4/8.
//  R7: fix R5's confounders: (a) launch_bounds(256,4) caused VGPR=64 cap ->
//      scratch spills (WRITE_SIZE 80->170MB) -> removed; (b) sg stride 24 (4-way
//      write bank conflict, 1.12M cycles) -> 28 (2-way=free); (c) manual 2-deep
//      phase-2 pipeline dropped (48 VGPRs); (d) zz[16] folded into acc.

#define F_IN 32
#define TT   16
#define CCH  64
#define FTN  512   // F_IN*TT floats per (b,n)
#define WPB  4     // waves per block in k_fused
#define WSTR 1792  // per-wave LDS floats: staging uses 1536, sg overlay 64*28=1792

__global__ void k_edge1(const int* __restrict__ row, const int* __restrict__ col,
                        float* __restrict__ deg, int* __restrict__ cnt,
                        int* __restrict__ pos, int E) {
    int i = blockIdx.x * 256 + threadIdx.x;
    if (i < E) {
        atomicAdd(&deg[row[i]], 1.0f);
        pos[i] = atomicAdd(&cnt[col[i]], 1);
    }
}

__global__ void k_scan(const int* __restrict__ cnt, int* __restrict__ rowptr, int n) {
    __shared__ int sdata[1024];
    int tid = threadIdx.x;
    int run = 0;
    for (int base = 0; base < n; base += 1024) {
        int v = (base + tid < n) ? cnt[base + tid] : 0;
        sdata[tid] = v;
        __syncthreads();
        for (int off = 1; off < 1024; off <<= 1) {
            int add = (tid >= off) ? sdata[tid - off] : 0;
            __syncthreads();
            sdata[tid] += add;
            __syncthreads();
        }
        int incl  = sdata[tid];
        int total = sdata[1023];
        if (base + tid < n) rowptr[base + tid] = run + incl - v;
        run += total;
        __syncthreads();
    }
    if (tid == 0) rowptr[n] = run;
}

__global__ void k_fill(const int* __restrict__ row, const int* __restrict__ col,
                       const float* __restrict__ deg, const int* __restrict__ rowptr,
                       const int* __restrict__ pos, int* __restrict__ srcs,
                       float* __restrict__ wsort, int E) {
    int i = blockIdx.x * 256 + threadIdx.x;
    if (i < E) {
        int r = row[i], c = col[i];
        float dr = deg[r], dc = deg[c];
        float w = 0.0f;
        if (dr > 0.0f && dc > 0.0f) w = -(rsqrtf(dr) * rsqrtf(dc));
        int slot = rowptr[c] + pos[i];
        srcs[slot]  = r;
        wsort[slot] = w;
    }
}

// Gather prop: one block per destination node. 256 threads x float4 = full
// B*F*T row of one source per iteration. 4-edge unroll for MLP. No atomics.
__global__ void k_prop(const float* __restrict__ zin, float* __restrict__ zout,
                       const int* __restrict__ rowptr, const int* __restrict__ srcs,
                       const float* __restrict__ wsort, int N) {
    int n   = blockIdx.x;
    int tid = threadIdx.x;                 // 0..255
    int beg = rowptr[n], end = rowptr[n + 1];
    const size_t bstride = (size_t)N * FTN;
    const size_t eoff = (size_t)(tid >> 7) * bstride + (size_t)(tid & 127) * 4;

    float4 a = make_float4(0.f, 0.f, 0.f, 0.f);
    int j = beg;
    for (; j + 3 < end; j += 4) {
        int   s0 = srcs[j],  s1 = srcs[j + 1], s2 = srcs[j + 2], s3 = srcs[j + 3];
        float w0 = wsort[j], w1 = wsort[j + 1], w2 = wsort[j + 2], w3 = wsort[j + 3];
        float4 v0 = *reinterpret_cast<const float4*>(zin + (size_t)s0 * FTN + eoff);
        float4 v1 = *reinterpret_cast<const float4*>(zin + (size_t)s1 * FTN + eoff);
        float4 v2 = *reinterpret_cast<const float4*>(zin + (size_t)s2 * FTN + eoff);
        float4 v3 = *reinterpret_cast<const float4*>(zin + (size_t)s3 * FTN + eoff);
        a.x = fmaf(w0, v0.x, fmaf(w1, v1.x, fmaf(w2, v2.x, fmaf(w3, v3.x, a.x))));
        a.y = fmaf(w0, v0.y, fmaf(w1, v1.y, fmaf(w2, v2.y, fmaf(w3, v3.y, a.y))));
        a.z = fmaf(w0, v0.z, fmaf(w1, v1.z, fmaf(w2, v2.z, fmaf(w3, v3.z, a.z))));
        a.w = fmaf(w0, v0.w, fmaf(w1, v1.w, fmaf(w2, v2.w, fmaf(w3, v3.w, a.w))));
    }
    for (; j < end; ++j) {
        int   s0 = srcs[j];
        float w0 = wsort[j];
        float4 v0 = *reinterpret_cast<const float4*>(zin + (size_t)s0 * FTN + eoff);
        a.x = fmaf(w0, v0.x, a.x);
        a.y = fmaf(w0, v0.y, a.y);
        a.z = fmaf(w0, v0.z, a.z);
        a.w = fmaf(w0, v0.w, a.w);
    }
    *reinterpret_cast<float4*>(zout + (size_t)n * FTN + eoff) = a;
}

// Weight prep:
//   pW4[f*64 + co]           = { W0-W2, W1, 2*W2, resW }          (2048 float4)
//   pTg[ci*48 + dt*16 + c0]  = { tw[co=c0], tw[c0+16], tw[c0+32], tw[c0+48] } (3072 float4)
__global__ void k_prep(const float* __restrict__ cheb_W, const float* __restrict__ time_W,
                       const float* __restrict__ res_W,
                       float4* __restrict__ pW4, float4* __restrict__ pTg) {
    int i = blockIdx.x * 256 + threadIdx.x;
    if (i < F_IN * 64) {
        int f = i >> 6, o = i & 63;
        float w0 = cheb_W[(0 * F_IN + f) * 64 + o];
        float w1 = cheb_W[(1 * F_IN + f) * 64 + o];
        float w2 = cheb_W[(2 * F_IN + f) * 64 + o];
        pW4[i] = make_float4(w0 - w2, w1, 2.0f * w2, res_W[o * F_IN + f]);
    }
    if (i < 64 * 3 * 16) {
        int ci = i / 48, r = i % 48, dt = r >> 4, c0 = r & 15;
        pTg[i] = make_float4(time_W[((c0      ) * 64 + ci) * 3 + dt],
                             time_W[((c0 + 16) * 64 + ci) * 3 + dt],
                             time_W[((c0 + 32) * 64 + ci) * 3 + dt],
                             time_W[((c0 + 48) * 64 + ci) * 3 + dt]);
    }
}

// phase-1 inner: one packed weight load + 16 FMA-triples for co-slot kk
#define P1K(kk)                                                                              \
    { float4 wv = pW4[f * 64 + c0 + 16 * kk];                                                \
      acc[kk*4+0] = fmaf(wv.x, xv.x, fmaf(wv.y, av.x, fmaf(wv.z, bv.x, acc[kk*4+0])));       \
      acc[kk*4+1] = fmaf(wv.x, xv.y, fmaf(wv.y, av.y, fmaf(wv.z, bv.y, acc[kk*4+1])));       \
      acc[kk*4+2] = fmaf(wv.x, xv.z, fmaf(wv.y, av.z, fmaf(wv.z, bv.z, acc[kk*4+2])));       \
      acc[kk*4+3] = fmaf(wv.x, xv.w, fmaf(wv.y, av.w, fmaf(wv.z, bv.w, acc[kk*4+3])));       \
      res[kk*4+0] = fmaf(wv.w, xv.x, res[kk*4+0]);                                           \
      res[kk*4+1] = fmaf(wv.w, xv.y, res[kk*4+1]);                                           \
      res[kk*4+2] = fmaf(wv.w, xv.z, res[kk*4+2]);                                           \
      res[kk*4+3] = fmaf(wv.w, xv.w, res[kk*4+3]); }

// phase-2 inner: co-slot kk, weight components w0c/w1c/w2c, window sm1..s4v
#define P2K(kk, w0c, w1c, w2c)                                                               \
    acc[kk*4+0] = fmaf(w0c, sm1, fmaf(w1c, s0v, fmaf(w2c, s1v, acc[kk*4+0])));               \
    acc[kk*4+1] = fmaf(w0c, s0v, fmaf(w1c, s1v, fmaf(w2c, s2v, acc[kk*4+1])));               \
    acc[kk*4+2] = fmaf(w0c, s1v, fmaf(w1c, s2v, fmaf(w2c, s3v, acc[kk*4+2])));               \
    acc[kk*4+3] = fmaf(w0c, s2v, fmaf(w1c, s3v, fmaf(w2c, s4v, acc[kk*4+3])));

#define P2COMP(W0, W1, W2, R0, R1, R2)                                                       \
    { float sm1 = R0.w, s0v = R1.x, s1v = R1.y, s2v = R1.z, s3v = R1.w, s4v = R2.x;          \
      P2K(0, W0.x, W1.x, W2.x)  P2K(1, W0.y, W1.y, W2.y)                                     \
      P2K(2, W0.z, W1.z, W2.z)  P2K(3, W0.w, W1.w, W2.w) }

// Fused per-(b,n) kernel. 256 threads = 4 waves; each wave owns one item (b,n).
// lane = (c0 = lane&15, tg = lane>>4): 4 co-slots x 4 timesteps per lane.
__global__ __launch_bounds__(256) void k_fused(
        const float* __restrict__ x, const float* __restrict__ P1, const float* __restrict__ P2,
        const float4* __restrict__ pW4, const float4* __restrict__ pTg,
        const float* __restrict__ cheb_b, const float* __restrict__ time_b,
        const float* __restrict__ res_b, const float* __restrict__ ln_g,
        const float* __restrict__ ln_b, float* __restrict__ out, int N) {
    __shared__ float smem[WPB * WSTR];
    int lane = threadIdx.x & 63;
    int wib  = threadIdx.x >> 6;
    int c0   = lane & 15;
    int tg   = lane >> 4;
    float*  st = smem + wib * WSTR;
    float4* s4 = reinterpret_cast<float4*>(st);   // staging: [0:128)=x, [128:256)=P1, [256:384)=P2

    // per-lane biases / LN params for its 4 co-slots (hoisted; item-independent)
    float chb[4], tb[4], rb[4], g[4], bb[4];
#pragma unroll
    for (int k = 0; k < 4; ++k) {
        chb[k] = cheb_b[c0 + 16 * k];
        tb[k]  = time_b[c0 + 16 * k];
        rb[k]  = res_b[c0 + 16 * k];
        g[k]   = ln_g[c0 + 16 * k];
        bb[k]  = ln_b[c0 + 16 * k];
    }

    int gw = blockIdx.x * WPB + wib;
    int nw = gridDim.x * WPB;
    int nitems = 2 * N;
    const size_t bstride = (size_t)N * FTN;

    for (int item = gw; item < nitems; item += nw) {
        int b = (item >= N) ? 1 : 0;
        int n = item - b * N;
        const float4* x4 = reinterpret_cast<const float4*>(x  + b * bstride + (size_t)n * FTN);
        const float4* a4 = reinterpret_cast<const float4*>(P1 + b * bstride + (size_t)n * FTN);
        const float4* b4 = reinterpret_cast<const float4*>(P2 + b * bstride + (size_t)n * FTN);

        // coalesced stage: 6 x (64 lanes x 16 B) = x,P1,P2 rows into LDS
        s4[lane]       = x4[lane];  s4[64 + lane]  = x4[64 + lane];
        s4[128 + lane] = a4[lane];  s4[192 + lane] = a4[64 + lane];
        s4[256 + lane] = b4[lane];  s4[320 + lane] = b4[64 + lane];

        float acc[16], res[16];
#pragma unroll
        for (int k = 0; k < 4; ++k)
#pragma unroll
            for (int j = 0; j < 4; ++j) { acc[k*4+j] = chb[k]; res[k*4+j] = rb[k]; }

        // phase 1: cheb einsum (3 mats) + residual 1x1. Per f: 3 DS reads
        // (4 distinct addrs: tg) + 4 packed VMEM weight loads + 64 FMA.
#pragma unroll 4
        for (int f = 0; f < F_IN; ++f) {
            float4 xv = s4[f * 4 + tg];
            float4 av = s4[128 + f * 4 + tg];
            float4 bv = s4[256 + f * 4 + tg];
            P1K(0) P1K(1) P1K(2) P1K(3)
        }

        // relu -> sg tile overlaying staging. Row ci: 28 floats (112 B: 16B-aligned
        // b128 cells, 28*c0 spans 8 banks -> 2-way conflict = free). idx3 = t(-1),
        // idx4..19 = t0..15, idx20 = t16.
#pragma unroll
        for (int k = 0; k < 4; ++k) {
            float4 sv = make_float4(fmaxf(acc[k*4+0], 0.f), fmaxf(acc[k*4+1], 0.f),
                                    fmaxf(acc[k*4+2], 0.f), fmaxf(acc[k*4+3], 0.f));
            *reinterpret_cast<float4*>(st + (c0 + 16 * k) * 28 + 4 + 4 * tg) = sv;
        }
        if (tg == 0) {
#pragma unroll
            for (int k = 0; k < 4; ++k) st[(c0 + 16 * k) * 28 + 3] = 0.f;
        } else if (tg == 1) {
#pragma unroll
            for (int k = 0; k < 4; ++k) st[(c0 + 16 * k) * 28 + 20] = 0.f;
        }

        // phase 2: temporal conv (kernel 3, pad 1). Per ci: 3 DS reads
        // (4 distinct addrs) + 3 packed VMEM weight loads + 48 FMA.
        // Plain loop; compiler schedules, TLP covers latency.
#pragma unroll
        for (int k = 0; k < 4; ++k)
#pragma unroll
            for (int j = 0; j < 4; ++j) acc[k*4+j] = res[k*4+j] + tb[k];

#pragma unroll 2
        for (int ci = 0; ci < 64; ++ci) {
            float4 w0 = pTg[ci * 48 + c0];
            float4 w1 = pTg[ci * 48 + 16 + c0];
            float4 w2 = pTg[ci * 48 + 32 + c0];
            const float4* sr = reinterpret_cast<const float4*>(st + ci * 28 + 4 * tg);
            float4 r0 = sr[0], r1 = sr[1], r2 = sr[2];
            P2COMP(w0, w1, w2, r0, r1, r2)
        }

        // relu + LayerNorm over co (4 in-lane slots x 16 lanes), xor 1/2/4/8 only
        float s1[4] = {0.f, 0.f, 0.f, 0.f}, s2[4] = {0.f, 0.f, 0.f, 0.f};
#pragma unroll
        for (int k = 0; k < 4; ++k)
#pragma unroll
            for (int j = 0; j < 4; ++j) {
                float v = fmaxf(acc[k*4+j], 0.f);
                acc[k*4+j] = v;
                s1[j] += v;
                s2[j] = fmaf(v, v, s2[j]);
            }
#pragma unroll
        for (int off = 1; off <= 8; off <<= 1)
#pragma unroll
            for (int j = 0; j < 4; ++j) {
                s1[j] += __shfl_xor(s1[j], off);
                s2[j] += __shfl_xor(s2[j], off);
            }
        float mu[4], rinv[4];
#pragma unroll
        for (int j = 0; j < 4; ++j) {
            mu[j] = s1[j] * (1.0f / 64.0f);
            float var = s2[j] * (1.0f / 64.0f) - mu[j] * mu[j];
            rinv[j] = rsqrtf(var + 1e-5f);
        }
        // write out[item][co][t]: per k one b128 at t=4tg..4tg+3 (contiguous 1KB/instr)
        float* ob = out + (size_t)item * 1024;
#pragma unroll
        for (int k = 0; k < 4; ++k) {
            float4 o;
            o.x = (acc[k*4+0] - mu[0]) * rinv[0] * g[k] + bb[k];
            o.y = (acc[k*4+1] - mu[1]) * rinv[1] * g[k] + bb[k];
            o.z = (acc[k*4+2] - mu[2]) * rinv[2] * g[k] + bb[k];
            o.w = (acc[k*4+3] - mu[3]) * rinv[3] * g[k] + bb[k];
            *reinterpret_cast<float4*>(ob + (c0 + 16 * k) * 16 + 4 * tg) = o;
        }
    }
}

extern "C" void kernel_launch(void* const* d_in, const int* in_sizes, int n_in,
                              void* d_out, int out_size, void* d_ws, size_t ws_size,
                              hipStream_t stream) {
    const float* x      = (const float*)d_in[0];
    const int*   ei     = (const int*)d_in[1];
    const float* cheb_W = (const float*)d_in[2];
    const float* cheb_b = (const float*)d_in[3];
    const float* time_W = (const float*)d_in[4];
    const float* time_b = (const float*)d_in[5];
    const float* res_W  = (const float*)d_in[6];
    const float* res_b  = (const float*)d_in[7];
    const float* ln_g   = (const float*)d_in[8];
    const float* ln_b   = (const float*)d_in[9];
    float* out = (float*)d_out;

    const int N = in_sizes[0] / (2 * F_IN * TT);   // B=2
    const int E = in_sizes[1] / 2;
    const int* row = ei;
    const int* col = ei + E;

    // workspace carve-out (256B aligned)
    char* w = (char*)d_ws;
    size_t off = 0;
    auto carve = [&](size_t bytes) { off = (off + 255) & ~(size_t)255; size_t o = off; off += bytes; return o; };
    float*  deg    = (float*) (w + carve((size_t)N * 4));
    int*    cnt    = (int*)   (w + carve((size_t)N * 4));
    int*    rowptr = (int*)   (w + carve((size_t)(N + 1) * 4));
    int*    pos    = (int*)   (w + carve((size_t)E * 4));
    int*    srcs   = (int*)   (w + carve((size_t)E * 4));
    float*  wsort  = (float*) (w + carve((size_t)E * 4));
    float4* pW4    = (float4*)(w + carve((size_t)F_IN * 64 * 16));
    float4* pTg    = (float4*)(w + carve((size_t)64 * 3 * 16 * 16));
    float*  P1     = (float*) (w + carve((size_t)2 * N * FTN * 4));
    float*  P2     = (float*) (w + carve((size_t)2 * N * FTN * 4));
    (void)ws_size; (void)n_in; (void)out_size;

    hipMemsetAsync(deg, 0, (size_t)N * 4, stream);
    hipMemsetAsync(cnt, 0, (size_t)N * 4, stream);

    int eb = (E + 255) / 256;
    k_edge1<<<eb, 256, 0, stream>>>(row, col, deg, cnt, pos, E);
    k_scan<<<1, 1024, 0, stream>>>(cnt, rowptr, N);
    k_fill<<<eb, 256, 0, stream>>>(row, col, deg, rowptr, pos, srcs, wsort, E);
    k_prop<<<N, 256, 0, stream>>>(x,  P1, rowptr, srcs, wsort, N);
    k_prop<<<N, 256, 0, stream>>>(P1, P2, rowptr, srcs, wsort, N);
    k_prep<<<16, 256, 0, stream>>>(cheb_W, time_W, res_W, pW4, pTg);

    int items  = 2 * N;
    int blocks = (items + WPB - 1) / WPB;   // 4 waves/block, 1 item/wave
    k_fused<<<blocks, 64 * WPB, 0, stream>>>(x, P1, P2, pW4, pTg,
                                             cheb_b, time_b, res_b, ln_g, ln_b, out, N);
}

// Round 9
// 604.409 us; speedup vs baseline: 1.0663x; 1.0325x over previous
//
#include <hip/hip_runtime.h>

// MSTGCN block, MI355X.
//  R2: 256-thread k_fused blocks. R3: LDS staging of x/P1/P2 (broadcast ds_read_b128).
//  R4: packed weights, 1 dwordx4 per loop step. BEST single-item: 278us @ 47% VALU.
//  R5/R7: lane re-partition experiment -> slower (307us): fewer DS ops but 3.3x
//      more weight VMEM; refuted DS-pipe-saturation theory. Reverted.
//  R8: R4 structure + TWO items per wave (adjacent n). Weight loads amortized
//      2x, every FMA block has 2 independent streams (ILP attacks the
//      dependency-latency diagnosis). LDS 2x (3 blocks/CU), VGPR ~110.

#define F_IN 32
#define TT   16
#define CCH  64
#define FTN  512   // F_IN*TT floats per (b,n)
#define WPB  4     // waves per block in k_fused
#define WSTR 1600  // per-item LDS floats (staging 1536 used, sg overlay 64*20=1280)

__global__ void k_edge1(const int* __restrict__ row, const int* __restrict__ col,
                        float* __restrict__ deg, int* __restrict__ cnt,
                        int* __restrict__ pos, int E) {
    int i = blockIdx.x * 256 + threadIdx.x;
    if (i < E) {
        atomicAdd(&deg[row[i]], 1.0f);
        pos[i] = atomicAdd(&cnt[col[i]], 1);
    }
}

__global__ void k_scan(const int* __restrict__ cnt, int* __restrict__ rowptr, int n) {
    __shared__ int sdata[1024];
    int tid = threadIdx.x;
    int run = 0;
    for (int base = 0; base < n; base += 1024) {
        int v = (base + tid < n) ? cnt[base + tid] : 0;
        sdata[tid] = v;
        __syncthreads();
        for (int off = 1; off < 1024; off <<= 1) {
            int add = (tid >= off) ? sdata[tid - off] : 0;
            __syncthreads();
            sdata[tid] += add;
            __syncthreads();
        }
        int incl  = sdata[tid];
        int total = sdata[1023];
        if (base + tid < n) rowptr[base + tid] = run + incl - v;
        run += total;
        __syncthreads();
    }
    if (tid == 0) rowptr[n] = run;
}

__global__ void k_fill(const int* __restrict__ row, const int* __restrict__ col,
                       const float* __restrict__ deg, const int* __restrict__ rowptr,
                       const int* __restrict__ pos, int* __restrict__ srcs,
                       float* __restrict__ wsort, int E) {
    int i = blockIdx.x * 256 + threadIdx.x;
    if (i < E) {
        int r = row[i], c = col[i];
        float dr = deg[r], dc = deg[c];
        float w = 0.0f;
        if (dr > 0.0f && dc > 0.0f) w = -(rsqrtf(dr) * rsqrtf(dc));
        int slot = rowptr[c] + pos[i];
        srcs[slot]  = r;
        wsort[slot] = w;
    }
}

// Gather prop: one block per destination node. 256 threads x float4 = full
// B*F*T row of one source per iteration. 4-edge unroll for MLP. No atomics.
__global__ void k_prop(const float* __restrict__ zin, float* __restrict__ zout,
                       const int* __restrict__ rowptr, const int* __restrict__ srcs,
                       const float* __restrict__ wsort, int N) {
    int n   = blockIdx.x;
    int tid = threadIdx.x;                 // 0..255
    int beg = rowptr[n], end = rowptr[n + 1];
    const size_t bstride = (size_t)N * FTN;
    const size_t eoff = (size_t)(tid >> 7) * bstride + (size_t)(tid & 127) * 4;

    float4 a = make_float4(0.f, 0.f, 0.f, 0.f);
    int j = beg;
    for (; j + 3 < end; j += 4) {
        int   s0 = srcs[j],  s1 = srcs[j + 1], s2 = srcs[j + 2], s3 = srcs[j + 3];
        float w0 = wsort[j], w1 = wsort[j + 1], w2 = wsort[j + 2], w3 = wsort[j + 3];
        float4 v0 = *reinterpret_cast<const float4*>(zin + (size_t)s0 * FTN + eoff);
        float4 v1 = *reinterpret_cast<const float4*>(zin + (size_t)s1 * FTN + eoff);
        float4 v2 = *reinterpret_cast<const float4*>(zin + (size_t)s2 * FTN + eoff);
        float4 v3 = *reinterpret_cast<const float4*>(zin + (size_t)s3 * FTN + eoff);
        a.x = fmaf(w0, v0.x, fmaf(w1, v1.x, fmaf(w2, v2.x, fmaf(w3, v3.x, a.x))));
        a.y = fmaf(w0, v0.y, fmaf(w1, v1.y, fmaf(w2, v2.y, fmaf(w3, v3.y, a.y))));
        a.z = fmaf(w0, v0.z, fmaf(w1, v1.z, fmaf(w2, v2.z, fmaf(w3, v3.z, a.z))));
        a.w = fmaf(w0, v0.w, fmaf(w1, v1.w, fmaf(w2, v2.w, fmaf(w3, v3.w, a.w))));
    }
    for (; j < end; ++j) {
        int   s0 = srcs[j];
        float w0 = wsort[j];
        float4 v0 = *reinterpret_cast<const float4*>(zin + (size_t)s0 * FTN + eoff);
        a.x = fmaf(w0, v0.x, a.x);
        a.y = fmaf(w0, v0.y, a.y);
        a.z = fmaf(w0, v0.z, a.z);
        a.w = fmaf(w0, v0.w, a.w);
    }
    *reinterpret_cast<float4*>(zout + (size_t)n * FTN + eoff) = a;
}

// Weight prep (packed float4 rows):
//   pW4[f][co] = { W0-W2, W1, 2*W2, resW }   (32*64 float4)
//   pT4[ci][co] = { tw_dt0, tw_dt1, tw_dt2, 0 }  (64*64 float4)
__global__ void k_prep(const float* __restrict__ cheb_W, const float* __restrict__ time_W,
                       const float* __restrict__ res_W,
                       float4* __restrict__ pW4, float4* __restrict__ pT4) {
    int i = blockIdx.x * 256 + threadIdx.x;
    if (i < F_IN * 64) {
        int f = i >> 6, o = i & 63;
        float w0 = cheb_W[(0 * F_IN + f) * 64 + o];
        float w1 = cheb_W[(1 * F_IN + f) * 64 + o];
        float w2 = cheb_W[(2 * F_IN + f) * 64 + o];
        pW4[i] = make_float4(w0 - w2, w1, 2.0f * w2, res_W[o * F_IN + f]);
    }
    if (i < 64 * 64) {
        int ci = i >> 6, co = i & 63;
        pT4[i] = make_float4(time_W[(co * 64 + ci) * 3 + 0],
                             time_W[(co * 64 + ci) * 3 + 1],
                             time_W[(co * 64 + ci) * 3 + 2], 0.0f);
    }
}

// Fused kernel: 256 threads = 4 waves; each wave owns TWO adjacent items.
// lane = output channel (64 = wave). Per item: stage x/P1/P2 coalesced into
// wave-private LDS, broadcast ds_read_b128 in the compute loops; weights one
// dwordx4 per loop step SHARED by both items.
__global__ __launch_bounds__(256) void k_fused(
        const float* __restrict__ x, const float* __restrict__ P1, const float* __restrict__ P2,
        const float4* __restrict__ pW4, const float4* __restrict__ pT4,
        const float* __restrict__ cheb_b, const float* __restrict__ time_b,
        const float* __restrict__ res_b, const float* __restrict__ ln_g,
        const float* __restrict__ ln_b, float* __restrict__ out, int N) {
    __shared__ float smem[WPB * 2 * WSTR];
    int lane = threadIdx.x & 63;
    int wib  = threadIdx.x >> 6;
    int co   = lane;
    float chb = cheb_b[co], tb = time_b[co], rb = res_b[co];
    float lng = ln_g[co],   lnb = ln_b[co];
    float*  stA = smem + wib * 2 * WSTR;
    float*  stB = stA + WSTR;
    float4* sA  = reinterpret_cast<float4*>(stA);
    float4* sB  = reinterpret_cast<float4*>(stB);

    int gp = blockIdx.x * WPB + wib;   // pair index; pairs = N (items = 2N)
    int np = gridDim.x * WPB;
    const size_t bstride = (size_t)N * FTN;

    for (int p = gp; p < N; p += np) {
        int i0 = 2 * p, i1 = 2 * p + 1;
        int b0 = (i0 >= N) ? 1 : 0;  int n0 = i0 - b0 * N;
        int b1 = (i1 >= N) ? 1 : 0;  int n1 = i1 - b1 * N;
        const float4* xA = reinterpret_cast<const float4*>(x  + b0 * bstride + (size_t)n0 * FTN);
        const float4* aA = reinterpret_cast<const float4*>(P1 + b0 * bstride + (size_t)n0 * FTN);
        const float4* bA = reinterpret_cast<const float4*>(P2 + b0 * bstride + (size_t)n0 * FTN);
        const float4* xB = reinterpret_cast<const float4*>(x  + b1 * bstride + (size_t)n1 * FTN);
        const float4* aB = reinterpret_cast<const float4*>(P1 + b1 * bstride + (size_t)n1 * FTN);
        const float4* bB = reinterpret_cast<const float4*>(P2 + b1 * bstride + (size_t)n1 * FTN);

        // coalesced stage: 12 x (64 lanes x 16 B) issued together
        sA[lane]       = xA[lane];  sA[64 + lane]  = xA[64 + lane];
        sA[128 + lane] = aA[lane];  sA[192 + lane] = aA[64 + lane];
        sA[256 + lane] = bA[lane];  sA[320 + lane] = bA[64 + lane];
        sB[lane]       = xB[lane];  sB[64 + lane]  = xB[64 + lane];
        sB[128 + lane] = aB[lane];  sB[192 + lane] = aB[64 + lane];
        sB[256 + lane] = bB[lane];  sB[320 + lane] = bB[64 + lane];

        float accA[16], resA[16], accB[16], resB[16];
#pragma unroll
        for (int t = 0; t < 16; ++t) {
            accA[t] = chb; resA[t] = rb;
            accB[t] = chb; resB[t] = rb;
        }

        // phase 1: cheb einsum + residual; one shared weight load per f
#pragma unroll 2
        for (int f = 0; f < F_IN; ++f) {
            float4 wv = pW4[f * 64 + co];
#pragma unroll
            for (int q = 0; q < 4; ++q) {
                float4 xv = sA[f * 4 + q];
                float4 av = sA[128 + f * 4 + q];
                float4 bv = sA[256 + f * 4 + q];
                accA[q*4+0] = fmaf(wv.x, xv.x, fmaf(wv.y, av.x, fmaf(wv.z, bv.x, accA[q*4+0])));
                accA[q*4+1] = fmaf(wv.x, xv.y, fmaf(wv.y, av.y, fmaf(wv.z, bv.y, accA[q*4+1])));
                accA[q*4+2] = fmaf(wv.x, xv.z, fmaf(wv.y, av.z, fmaf(wv.z, bv.z, accA[q*4+2])));
                accA[q*4+3] = fmaf(wv.x, xv.w, fmaf(wv.y, av.w, fmaf(wv.z, bv.w, accA[q*4+3])));
                resA[q*4+0] = fmaf(wv.w, xv.x, resA[q*4+0]);
                resA[q*4+1] = fmaf(wv.w, xv.y, resA[q*4+1]);
                resA[q*4+2] = fmaf(wv.w, xv.z, resA[q*4+2]);
                resA[q*4+3] = fmaf(wv.w, xv.w, resA[q*4+3]);
                float4 xw = sB[f * 4 + q];
                float4 aw = sB[128 + f * 4 + q];
                float4 bw = sB[256 + f * 4 + q];
                accB[q*4+0] = fmaf(wv.x, xw.x, fmaf(wv.y, aw.x, fmaf(wv.z, bw.x, accB[q*4+0])));
                accB[q*4+1] = fmaf(wv.x, xw.y, fmaf(wv.y, aw.y, fmaf(wv.z, bw.y, accB[q*4+1])));
                accB[q*4+2] = fmaf(wv.x, xw.z, fmaf(wv.y, aw.z, fmaf(wv.z, bw.z, accB[q*4+2])));
                accB[q*4+3] = fmaf(wv.x, xw.w, fmaf(wv.y, aw.w, fmaf(wv.z, bw.w, accB[q*4+3])));
                resB[q*4+0] = fmaf(wv.w, xw.x, resB[q*4+0]);
                resB[q*4+1] = fmaf(wv.w, xw.y, resB[q*4+1]);
                resB[q*4+2] = fmaf(wv.w, xw.z, resB[q*4+2]);
                resB[q*4+3] = fmaf(wv.w, xw.w, resB[q*4+3]);
            }
        }

        // relu -> sg tiles (overlay staging; stride 20, same pattern as R4)
        stA[co * 20 + 0] = 0.f; stA[co * 20 + 17] = 0.f;
        stA[co * 20 + 18] = 0.f; stA[co * 20 + 19] = 0.f;
        stB[co * 20 + 0] = 0.f; stB[co * 20 + 17] = 0.f;
        stB[co * 20 + 18] = 0.f; stB[co * 20 + 19] = 0.f;
#pragma unroll
        for (int t = 0; t < 16; ++t) {
            stA[co * 20 + t + 1] = fmaxf(accA[t], 0.f);
            stB[co * 20 + t + 1] = fmaxf(accB[t], 0.f);
        }

        // phase 2: temporal conv; one shared weight load per ci
#pragma unroll
        for (int t = 0; t < 16; ++t) {
            accA[t] = resA[t] + tb;
            accB[t] = resB[t] + tb;
        }
        for (int ci = 0; ci < 64; ++ci) {
            float4 tv = pT4[ci * 64 + co];
            const float4* srA = reinterpret_cast<const float4*>(stA + ci * 20);
            float4 p0 = srA[0], p1 = srA[1], p2 = srA[2], p3 = srA[3], p4 = srA[4];
            float sa[20] = { p0.x,p0.y,p0.z,p0.w, p1.x,p1.y,p1.z,p1.w,
                             p2.x,p2.y,p2.z,p2.w, p3.x,p3.y,p3.z,p3.w,
                             p4.x,p4.y,p4.z,p4.w };
#pragma unroll
            for (int t = 0; t < 16; ++t)
                accA[t] = fmaf(tv.x, sa[t], fmaf(tv.y, sa[t + 1], fmaf(tv.z, sa[t + 2], accA[t])));
            const float4* srB = reinterpret_cast<const float4*>(stB + ci * 20);
            float4 q0 = srB[0], q1 = srB[1], q2 = srB[2], q3 = srB[3], q4 = srB[4];
            float sb[20] = { q0.x,q0.y,q0.z,q0.w, q1.x,q1.y,q1.z,q1.w,
                             q2.x,q2.y,q2.z,q2.w, q3.x,q3.y,q3.z,q3.w,
                             q4.x,q4.y,q4.z,q4.w };
#pragma unroll
            for (int t = 0; t < 16; ++t)
                accB[t] = fmaf(tv.x, sb[t], fmaf(tv.y, sb[t + 1], fmaf(tv.z, sb[t + 2], accB[t])));
        }

        // relu + LayerNorm (over co = 64 lanes) + transposed store, both items
        float* obA = out + (size_t)i0 * 1024;
        float* obB = out + (size_t)i1 * 1024;
        float zA[16], zB[16];
#pragma unroll
        for (int t = 0; t < 16; ++t) {
            float vA = fmaxf(accA[t], 0.f);
            float vB = fmaxf(accB[t], 0.f);
            float sA1 = vA, sA2 = vA * vA, sB1 = vB, sB2 = vB * vB;
#pragma unroll
            for (int off = 32; off >= 1; off >>= 1) {
                sA1 += __shfl_xor(sA1, off);
                sA2 += __shfl_xor(sA2, off);
                sB1 += __shfl_xor(sB1, off);
                sB2 += __shfl_xor(sB2, off);
            }
            float muA  = sA1 * (1.0f / 64.0f);
            float varA = sA2 * (1.0f / 64.0f) - muA * muA;
            zA[t] = (vA - muA) * rsqrtf(varA + 1e-5f) * lng + lnb;
            float muB  = sB1 * (1.0f / 64.0f);
            float varB = sB2 * (1.0f / 64.0f) - muB * muB;
            zB[t] = (vB - muB) * rsqrtf(varB + 1e-5f) * lng + lnb;
        }
        float4* oA = reinterpret_cast<float4*>(obA + co * 16);
        oA[0] = make_float4(zA[0],  zA[1],  zA[2],  zA[3]);
        oA[1] = make_float4(zA[4],  zA[5],  zA[6],  zA[7]);
        oA[2] = make_float4(zA[8],  zA[9],  zA[10], zA[11]);
        oA[3] = make_float4(zA[12], zA[13], zA[14], zA[15]);
        float4* oB = reinterpret_cast<float4*>(obB + co * 16);
        oB[0] = make_float4(zB[0],  zB[1],  zB[2],  zB[3]);
        oB[1] = make_float4(zB[4],  zB[5],  zB[6],  zB[7]);
        oB[2] = make_float4(zB[8],  zB[9],  zB[10], zB[11]);
        oB[3] = make_float4(zB[12], zB[13], zB[14], zB[15]);
    }
}

extern "C" void kernel_launch(void* const* d_in, const int* in_sizes, int n_in,
                              void* d_out, int out_size, void* d_ws, size_t ws_size,
                              hipStream_t stream) {
    const float* x      = (const float*)d_in[0];
    const int*   ei     = (const int*)d_in[1];
    const float* cheb_W = (const float*)d_in[2];
    const float* cheb_b = (const float*)d_in[3];
    const float* time_W = (const float*)d_in[4];
    const float* time_b = (const float*)d_in[5];
    const float* res_W  = (const float*)d_in[6];
    const float* res_b  = (const float*)d_in[7];
    const float* ln_g   = (const float*)d_in[8];
    const float* ln_b   = (const float*)d_in[9];
    float* out = (float*)d_out;

    const int N = in_sizes[0] / (2 * F_IN * TT);   // B=2
    const int E = in_sizes[1] / 2;
    const int* row = ei;
    const int* col = ei + E;

    // workspace carve-out (256B aligned)
    char* w = (char*)d_ws;
    size_t off = 0;
    auto carve = [&](size_t bytes) { off = (off + 255) & ~(size_t)255; size_t o = off; off += bytes; return o; };
    float*  deg    = (float*) (w + carve((size_t)N * 4));
    int*    cnt    = (int*)   (w + carve((size_t)N * 4));
    int*    rowptr = (int*)   (w + carve((size_t)(N + 1) * 4));
    int*    pos    = (int*)   (w + carve((size_t)E * 4));
    int*    srcs   = (int*)   (w + carve((size_t)E * 4));
    float*  wsort  = (float*) (w + carve((size_t)E * 4));
    float4* pW4    = (float4*)(w + carve((size_t)F_IN * 64 * 16));
    float4* pT4    = (float4*)(w + carve((size_t)64 * 64 * 16));
    float*  P1     = (float*) (w + carve((size_t)2 * N * FTN * 4));
    float*  P2     = (float*) (w + carve((size_t)2 * N * FTN * 4));
    (void)ws_size; (void)n_in; (void)out_size;

    hipMemsetAsync(deg, 0, (size_t)N * 4, stream);
    hipMemsetAsync(cnt, 0, (size_t)N * 4, stream);

    int eb = (E + 255) / 256;
    k_edge1<<<eb, 256, 0, stream>>>(row, col, deg, cnt, pos, E);
    k_scan<<<1, 1024, 0, stream>>>(cnt, rowptr, N);
    k_fill<<<eb, 256, 0, stream>>>(row, col, deg, rowptr, pos, srcs, wsort, E);
    k_prop<<<N, 256, 0, stream>>>(x,  P1, rowptr, srcs, wsort, N);
    k_prop<<<N, 256, 0, stream>>>(P1, P2, rowptr, srcs, wsort, N);
    k_prep<<<16, 256, 0, stream>>>(cheb_W, time_W, res_W, pW4, pT4);

    int pairs  = N;                          // 2N items, 2 per wave
    int blocks = (pairs + WPB - 1) / WPB;    // 4 waves/block
    k_fused<<<blocks, 64 * WPB, 0, stream>>>(x, P1, P2, pW4, pT4,
                                             cheb_b, time_b, res_b, ln_g, ln_b, out, N);
}

// Round 10
// 477.182 us; speedup vs baseline: 1.3506x; 1.2666x over previous
//
#include <hip/hip_runtime.h>

// MSTGCN block, MI355X.
//  R2-R8 ledger: best VALU-only k_fused = 278us @ 45-47% VALUBusy across ALL
//  structural variants (occupancy/VMEM/DS/ILP levers all neutral) -> vector
//  pipe structure is the ceiling; MfmaUtil was 0.
//  R9: k_fused rewritten on MFMA (mfma_f32_16x16x32_bf16, split-bf16 hi+lo,
//  3-term products, fp32 accumulate). Per item (1 wave): phase1 = K=96 GEMM
//  (x|P1|P2) + K=32 residual GEMM; phase2 = 3 GEMMs (K=64 each, one per tap)
//  vs fp32 sgT[t][ci] LDS tile, combined by post-GEMM t-shifts.
//  A-frags: per-lane global loads with OUR k-mapping (f = g*8+j); B-frags
//  precomputed with the IDENTICAL mapping (k-permutation-invariant).
//  Verified layouts used: A m=lane&15, B n=lane&15, D col=lane&15 row=(g)*4+reg.

#define F_IN 32
#define TT   16
#define FTN  512   // F_IN*TT floats per (b,n)
#define WPB  4     // waves per block in k_fused

typedef __attribute__((ext_vector_type(8))) short bf16x8;
typedef __attribute__((ext_vector_type(4))) float f32x4;
#define MFMA __builtin_amdgcn_mfma_f32_16x16x32_bf16

__device__ __forceinline__ unsigned short f2bf(float v) {
    unsigned int u = __float_as_uint(v);
    unsigned int r = (u + 0x7FFFu + ((u >> 16) & 1u)) >> 16;   // RNE
    return (unsigned short)r;
}
__device__ __forceinline__ float bf2f(unsigned short h) {
    return __uint_as_float(((unsigned int)h) << 16);
}

__global__ void k_edge1(const int* __restrict__ row, const int* __restrict__ col,
                        float* __restrict__ deg, int* __restrict__ cnt,
                        int* __restrict__ pos, int E) {
    int i = blockIdx.x * 256 + threadIdx.x;
    if (i < E) {
        atomicAdd(&deg[row[i]], 1.0f);
        pos[i] = atomicAdd(&cnt[col[i]], 1);
    }
}

__global__ void k_scan(const int* __restrict__ cnt, int* __restrict__ rowptr, int n) {
    __shared__ int sdata[1024];
    int tid = threadIdx.x;
    int run = 0;
    for (int base = 0; base < n; base += 1024) {
        int v = (base + tid < n) ? cnt[base + tid] : 0;
        sdata[tid] = v;
        __syncthreads();
        for (int off = 1; off < 1024; off <<= 1) {
            int add = (tid >= off) ? sdata[tid - off] : 0;
            __syncthreads();
            sdata[tid] += add;
            __syncthreads();
        }
        int incl  = sdata[tid];
        int total = sdata[1023];
        if (base + tid < n) rowptr[base + tid] = run + incl - v;
        run += total;
        __syncthreads();
    }
    if (tid == 0) rowptr[n] = run;
}

__global__ void k_fill(const int* __restrict__ row, const int* __restrict__ col,
                       const float* __restrict__ deg, const int* __restrict__ rowptr,
                       const int* __restrict__ pos, int* __restrict__ srcs,
                       float* __restrict__ wsort, int E) {
    int i = blockIdx.x * 256 + threadIdx.x;
    if (i < E) {
        int r = row[i], c = col[i];
        float dr = deg[r], dc = deg[c];
        float w = 0.0f;
        if (dr > 0.0f && dc > 0.0f) w = -(rsqrtf(dr) * rsqrtf(dc));
        int slot = rowptr[c] + pos[i];
        srcs[slot]  = r;
        wsort[slot] = w;
    }
}

// Gather prop: one block per destination node. 256 threads x float4 = full
// B*F*T row of one source per iteration. 4-edge unroll for MLP. No atomics.
__global__ void k_prop(const float* __restrict__ zin, float* __restrict__ zout,
                       const int* __restrict__ rowptr, const int* __restrict__ srcs,
                       const float* __restrict__ wsort, int N) {
    int n   = blockIdx.x;
    int tid = threadIdx.x;
    int beg = rowptr[n], end = rowptr[n + 1];
    const size_t bstride = (size_t)N * FTN;
    const size_t eoff = (size_t)(tid >> 7) * bstride + (size_t)(tid & 127) * 4;

    float4 a = make_float4(0.f, 0.f, 0.f, 0.f);
    int j = beg;
    for (; j + 3 < end; j += 4) {
        int   s0 = srcs[j],  s1 = srcs[j + 1], s2 = srcs[j + 2], s3 = srcs[j + 3];
        float w0 = wsort[j], w1 = wsort[j + 1], w2 = wsort[j + 2], w3 = wsort[j + 3];
        float4 v0 = *reinterpret_cast<const float4*>(zin + (size_t)s0 * FTN + eoff);
        float4 v1 = *reinterpret_cast<const float4*>(zin + (size_t)s1 * FTN + eoff);
        float4 v2 = *reinterpret_cast<const float4*>(zin + (size_t)s2 * FTN + eoff);
        float4 v3 = *reinterpret_cast<const float4*>(zin + (size_t)s3 * FTN + eoff);
        a.x = fmaf(w0, v0.x, fmaf(w1, v1.x, fmaf(w2, v2.x, fmaf(w3, v3.x, a.x))));
        a.y = fmaf(w0, v0.y, fmaf(w1, v1.y, fmaf(w2, v2.y, fmaf(w3, v3.y, a.y))));
        a.z = fmaf(w0, v0.z, fmaf(w1, v1.z, fmaf(w2, v2.z, fmaf(w3, v3.z, a.z))));
        a.w = fmaf(w0, v0.w, fmaf(w1, v1.w, fmaf(w2, v2.w, fmaf(w3, v3.w, a.w))));
    }
    for (; j < end; ++j) {
        int   s0 = srcs[j];
        float w0 = wsort[j];
        float4 v0 = *reinterpret_cast<const float4*>(zin + (size_t)s0 * FTN + eoff);
        a.x = fmaf(w0, v0.x, a.x);
        a.y = fmaf(w0, v0.y, a.y);
        a.z = fmaf(w0, v0.z, a.z);
        a.w = fmaf(w0, v0.w, a.w);
    }
    *reinterpret_cast<float4*>(zout + (size_t)n * FTN + eoff) = a;
}

__device__ __forceinline__ uint4 pack_frag(const float* w, int h) {
    unsigned short s[8];
#pragma unroll
    for (int j = 0; j < 8; ++j) {
        float v = w[j];
        unsigned short hi = f2bf(v);
        s[j] = h ? f2bf(v - bf2f(hi)) : hi;
    }
    uint4 u;
    u.x = (unsigned)s[0] | ((unsigned)s[1] << 16);
    u.y = (unsigned)s[2] | ((unsigned)s[3] << 16);
    u.z = (unsigned)s[4] | ((unsigned)s[5] << 16);
    u.w = (unsigned)s[6] | ((unsigned)s[7] << 16);
    return u;
}

// Weight B-fragment precompute. k-slot mapping (shared with A side):
//   lane = g*16 + mm (g=lane>>4, mm=lane&15 = n = co_low), slot j=0..7 -> k = g*8 + j.
//   pBa[ks(3)][nt(4)][h(2)][lane]: ks0: W0-W2 (x), ks1: W1 (P1), ks2: 2*W2 (P2)
//   pBr[nt(4)][h(2)][lane]:        res_W (K=32, x)
//   pBt[dt(3)][ks(2)][nt(4)][h(2)][lane]: time_W tap dt, ci = ks*32 + g*8 + j
__global__ void k_prepf(const float* __restrict__ cheb_W, const float* __restrict__ time_W,
                        const float* __restrict__ res_W,
                        uint4* __restrict__ pBa, uint4* __restrict__ pBr,
                        uint4* __restrict__ pBt) {
    int tid = blockIdx.x * 256 + threadIdx.x;
    if (tid >= 5120) return;
    int lane = tid & 63, g = lane >> 4, mm = lane & 15;
    float w[8];
    if (tid < 1536) {
        int fa = tid >> 6;
        int h = fa & 1, nt = (fa >> 1) & 3, ks = fa >> 3;
        int co = nt * 16 + mm;
#pragma unroll
        for (int j = 0; j < 8; ++j) {
            int f = g * 8 + j;
            float v;
            if (ks == 0)      v = cheb_W[f * 64 + co] - cheb_W[4096 + f * 64 + co];
            else if (ks == 1) v = cheb_W[2048 + f * 64 + co];
            else              v = 2.0f * cheb_W[4096 + f * 64 + co];
            w[j] = v;
        }
        pBa[fa * 64 + lane] = pack_frag(w, h);
    } else if (tid < 2048) {
        int fr = (tid - 1536) >> 6;
        int h = fr & 1, nt = fr >> 1;
        int co = nt * 16 + mm;
#pragma unroll
        for (int j = 0; j < 8; ++j) w[j] = res_W[co * 32 + (g * 8 + j)];
        pBr[fr * 64 + lane] = pack_frag(w, h);
    } else {
        int ft = (tid - 2048) >> 6;
        int h = ft & 1, nt = (ft >> 1) & 3, ks = (ft >> 3) & 1, dt = ft >> 4;
        int co = nt * 16 + mm;
#pragma unroll
        for (int j = 0; j < 8; ++j) {
            int ci = ks * 32 + g * 8 + j;
            w[j] = time_W[(co * 64 + ci) * 3 + dt];
        }
        pBt[ft * 64 + lane] = pack_frag(w, h);
    }
}

// Fused MFMA kernel: 256 threads = 4 waves, one item (b,n) per wave.
// Tile: D[16 t][64 co] as 4 N-tiles of 16x16. Lane: g=lane>>4, mm=lane&15.
// A-frags: m = mm, k-slot j -> our mapping. D: row t=(g*4+reg), col co_low=mm.
__global__ __launch_bounds__(256) void k_fused(
        const float* __restrict__ x, const float* __restrict__ P1, const float* __restrict__ P2,
        const uint4* __restrict__ pBa, const uint4* __restrict__ pBr,
        const uint4* __restrict__ pBt,
        const float* __restrict__ cheb_b, const float* __restrict__ time_b,
        const float* __restrict__ res_b, const float* __restrict__ ln_g,
        const float* __restrict__ ln_b, float* __restrict__ out, int N) {
    __shared__ float sgAll[WPB][16][68];   // per-wave fp32 sg^T tile [t][ci], pad 68
    int lane = threadIdx.x & 63;
    int wib  = threadIdx.x >> 6;
    int g    = lane >> 4;
    int mm   = lane & 15;
    float (*sgT)[68] = sgAll[wib];

    // per-lane per-nt params (co = nt*16 + mm)
    float chb[4], tbb[4], rbb[4], lng[4], lnb[4];
#pragma unroll
    for (int nt = 0; nt < 4; ++nt) {
        int co = nt * 16 + mm;
        chb[nt] = cheb_b[co]; tbb[nt] = time_b[co]; rbb[nt] = res_b[co];
        lng[nt] = ln_g[co];   lnb[nt] = ln_b[co];
    }

    int gw = blockIdx.x * WPB + wib;
    int nw = gridDim.x * WPB;
    int nitems = 2 * N;
    const size_t bstride = (size_t)N * FTN;

    for (int item = gw; item < nitems; item += nw) {
        int b = (item >= N) ? 1 : 0;
        int n = item - b * N;
        const float* bx  = x  + b * bstride + (size_t)n * FTN;
        const float* bp1 = P1 + b * bstride + (size_t)n * FTN;
        const float* bp2 = P2 + b * bstride + (size_t)n * FTN;

        // A1 fragments: per-lane global loads, f = g*8+j, t = mm
        float a1[3][8];
#pragma unroll
        for (int j = 0; j < 8; ++j) {
            int off = (g * 8 + j) * 16 + mm;
            a1[0][j] = bx[off];
            a1[1][j] = bp1[off];
            a1[2][j] = bp2[off];
        }
        bf16x8 a1h[3], a1l[3];
#pragma unroll
        for (int ks = 0; ks < 3; ++ks)
#pragma unroll
            for (int j = 0; j < 8; ++j) {
                float v = a1[ks][j];
                unsigned short hi = f2bf(v);
                a1h[ks][j] = (short)hi;
                a1l[ks][j] = (short)f2bf(v - bf2f(hi));
            }

        // phase 1: acc GEMM (K=96) + res GEMM (K=32), split-bf16 3-term
        f32x4 acc[4], res[4];
#pragma unroll
        for (int nt = 0; nt < 4; ++nt) { acc[nt] = (f32x4){0,0,0,0}; res[nt] = (f32x4){0,0,0,0}; }
#pragma unroll
        for (int ks = 0; ks < 3; ++ks)
#pragma unroll
            for (int nt = 0; nt < 4; ++nt) {
                bf16x8 bh = *reinterpret_cast<const bf16x8*>(&pBa[((ks*4+nt)*2 + 0)*64 + lane]);
                bf16x8 bl = *reinterpret_cast<const bf16x8*>(&pBa[((ks*4+nt)*2 + 1)*64 + lane]);
                acc[nt] = MFMA(a1h[ks], bh, acc[nt], 0, 0, 0);
                acc[nt] = MFMA(a1l[ks], bh, acc[nt], 0, 0, 0);
                acc[nt] = MFMA(a1h[ks], bl, acc[nt], 0, 0, 0);
            }
#pragma unroll
        for (int nt = 0; nt < 4; ++nt) {
            bf16x8 bh = *reinterpret_cast<const bf16x8*>(&pBr[(nt*2 + 0)*64 + lane]);
            bf16x8 bl = *reinterpret_cast<const bf16x8*>(&pBr[(nt*2 + 1)*64 + lane]);
            res[nt] = MFMA(a1h[0], bh, res[nt], 0, 0, 0);
            res[nt] = MFMA(a1l[0], bh, res[nt], 0, 0, 0);
            res[nt] = MFMA(a1h[0], bl, res[nt], 0, 0, 0);
        }

        // sg = relu(acc + cheb_b) -> fp32 LDS tile sgT[t][ci]  (wave-private)
#pragma unroll
        for (int nt = 0; nt < 4; ++nt) {
            int co = nt * 16 + mm;
            sgT[g*4 + 0][co] = fmaxf(acc[nt].x + chb[nt], 0.f);
            sgT[g*4 + 1][co] = fmaxf(acc[nt].y + chb[nt], 0.f);
            sgT[g*4 + 2][co] = fmaxf(acc[nt].z + chb[nt], 0.f);
            sgT[g*4 + 3][co] = fmaxf(acc[nt].w + chb[nt], 0.f);
        }

        // A2 fragments from sgT: m = mm (t), k = ci = ks*32 + g*8 + j
        bf16x8 a2h[2], a2l[2];
#pragma unroll
        for (int ks = 0; ks < 2; ++ks) {
            const float* rp = &sgT[mm][ks*32 + g*8];
            float4 v0 = *reinterpret_cast<const float4*>(rp);
            float4 v1 = *reinterpret_cast<const float4*>(rp + 4);
            float vv[8] = {v0.x, v0.y, v0.z, v0.w, v1.x, v1.y, v1.z, v1.w};
#pragma unroll
            for (int j = 0; j < 8; ++j) {
                unsigned short hi = f2bf(vv[j]);
                a2h[ks][j] = (short)hi;
                a2l[ks][j] = (short)f2bf(vv[j] - bf2f(hi));
            }
        }

        // out accumulator init: residual + biases
        f32x4 oA[4];
#pragma unroll
        for (int nt = 0; nt < 4; ++nt) {
            oA[nt].x = res[nt].x + rbb[nt] + tbb[nt];
            oA[nt].y = res[nt].y + rbb[nt] + tbb[nt];
            oA[nt].z = res[nt].z + rbb[nt] + tbb[nt];
            oA[nt].w = res[nt].w + rbb[nt] + tbb[nt];
        }

        // phase 2: 3 tap-GEMMs (K=64), combined with t-shifts
#pragma unroll
        for (int dt = 0; dt < 3; ++dt) {
            f32x4 D[4];
#pragma unroll
            for (int nt = 0; nt < 4; ++nt) D[nt] = (f32x4){0,0,0,0};
#pragma unroll
            for (int ks = 0; ks < 2; ++ks)
#pragma unroll
                for (int nt = 0; nt < 4; ++nt) {
                    int ft = ((dt*2 + ks)*4 + nt)*2;
                    bf16x8 bh = *reinterpret_cast<const bf16x8*>(&pBt[(ft + 0)*64 + lane]);
                    bf16x8 bl = *reinterpret_cast<const bf16x8*>(&pBt[(ft + 1)*64 + lane]);
                    D[nt] = MFMA(a2h[ks], bh, D[nt], 0, 0, 0);
                    D[nt] = MFMA(a2l[ks], bh, D[nt], 0, 0, 0);
                    D[nt] = MFMA(a2h[ks], bl, D[nt], 0, 0, 0);
                }
            if (dt == 1) {
#pragma unroll
                for (int nt = 0; nt < 4; ++nt) {
                    oA[nt].x += D[nt].x; oA[nt].y += D[nt].y;
                    oA[nt].z += D[nt].z; oA[nt].w += D[nt].w;
                }
            } else if (dt == 0) {   // out[t] += D[t-1]
#pragma unroll
                for (int nt = 0; nt < 4; ++nt) {
                    float up = __shfl(D[nt].w, lane - 16);
                    oA[nt].x += (g == 0) ? 0.f : up;
                    oA[nt].y += D[nt].x; oA[nt].z += D[nt].y; oA[nt].w += D[nt].z;
                }
            } else {                // dt==2: out[t] += D[t+1]
#pragma unroll
                for (int nt = 0; nt < 4; ++nt) {
                    float dn = __shfl(D[nt].x, lane + 16);
                    oA[nt].x += D[nt].y; oA[nt].y += D[nt].z; oA[nt].z += D[nt].w;
                    oA[nt].w += (g == 3) ? 0.f : dn;
                }
            }
        }

        // relu + LayerNorm over co (in-lane nt partials + xor over mm lanes)
        float s1[4] = {0,0,0,0}, s2[4] = {0,0,0,0};
#pragma unroll
        for (int nt = 0; nt < 4; ++nt) {
            oA[nt].x = fmaxf(oA[nt].x, 0.f); s1[0] += oA[nt].x; s2[0] = fmaf(oA[nt].x, oA[nt].x, s2[0]);
            oA[nt].y = fmaxf(oA[nt].y, 0.f); s1[1] += oA[nt].y; s2[1] = fmaf(oA[nt].y, oA[nt].y, s2[1]);
            oA[nt].z = fmaxf(oA[nt].z, 0.f); s1[2] += oA[nt].z; s2[2] = fmaf(oA[nt].z, oA[nt].z, s2[2]);
            oA[nt].w = fmaxf(oA[nt].w, 0.f); s1[3] += oA[nt].w; s2[3] = fmaf(oA[nt].w, oA[nt].w, s2[3]);
        }
#pragma unroll
        for (int off = 1; off <= 8; off <<= 1)
#pragma unroll
            for (int r = 0; r < 4; ++r) {
                s1[r] += __shfl_xor(s1[r], off);
                s2[r] += __shfl_xor(s2[r], off);
            }
        float mu[4], ri[4];
#pragma unroll
        for (int r = 0; r < 4; ++r) {
            mu[r] = s1[r] * (1.0f / 64.0f);
            float var = s2[r] * (1.0f / 64.0f) - mu[r] * mu[r];
            ri[r] = rsqrtf(var + 1e-5f);
        }
        // store out[item][co][t]: per nt one float4 at t = g*4..g*4+3 (1KB/wave coalesced)
        float* ob = out + (size_t)item * 1024;
#pragma unroll
        for (int nt = 0; nt < 4; ++nt) {
            float4 o;
            o.x = (oA[nt].x - mu[0]) * ri[0] * lng[nt] + lnb[nt];
            o.y = (oA[nt].y - mu[1]) * ri[1] * lng[nt] + lnb[nt];
            o.z = (oA[nt].z - mu[2]) * ri[2] * lng[nt] + lnb[nt];
            o.w = (oA[nt].w - mu[3]) * ri[3] * lng[nt] + lnb[nt];
            *reinterpret_cast<float4*>(ob + (nt*16 + mm)*16 + g*4) = o;
        }
    }
}

extern "C" void kernel_launch(void* const* d_in, const int* in_sizes, int n_in,
                              void* d_out, int out_size, void* d_ws, size_t ws_size,
                              hipStream_t stream) {
    const float* x      = (const float*)d_in[0];
    const int*   ei     = (const int*)d_in[1];
    const float* cheb_W = (const float*)d_in[2];
    const float* cheb_b = (const float*)d_in[3];
    const float* time_W = (const float*)d_in[4];
    const float* time_b = (const float*)d_in[5];
    const float* res_W  = (const float*)d_in[6];
    const float* res_b  = (const float*)d_in[7];
    const float* ln_g   = (const float*)d_in[8];
    const float* ln_b   = (const float*)d_in[9];
    float* out = (float*)d_out;

    const int N = in_sizes[0] / (2 * F_IN * TT);   // B=2
    const int E = in_sizes[1] / 2;
    const int* row = ei;
    const int* col = ei + E;

    // workspace carve-out (256B aligned)
    char* w = (char*)d_ws;
    size_t off = 0;
    auto carve = [&](size_t bytes) { off = (off + 255) & ~(size_t)255; size_t o = off; off += bytes; return o; };
    float* deg    = (float*)(w + carve((size_t)N * 4));
    int*   cnt    = (int*)  (w + carve((size_t)N * 4));
    int*   rowptr = (int*)  (w + carve((size_t)(N + 1) * 4));
    int*   pos    = (int*)  (w + carve((size_t)E * 4));
    int*   srcs   = (int*)  (w + carve((size_t)E * 4));
    float* wsort  = (float*)(w + carve((size_t)E * 4));
    uint4* pBa    = (uint4*)(w + carve((size_t)24 * 64 * 16));
    uint4* pBr    = (uint4*)(w + carve((size_t)8  * 64 * 16));
    uint4* pBt    = (uint4*)(w + carve((size_t)48 * 64 * 16));
    float* P1     = (float*)(w + carve((size_t)2 * N * FTN * 4));
    float* P2     = (float*)(w + carve((size_t)2 * N * FTN * 4));
    (void)ws_size; (void)n_in; (void)out_size;

    hipMemsetAsync(deg, 0, (size_t)N * 4, stream);
    hipMemsetAsync(cnt, 0, (size_t)N * 4, stream);

    int eb = (E + 255) / 256;
    k_edge1<<<eb, 256, 0, stream>>>(row, col, deg, cnt, pos, E);
    k_scan<<<1, 1024, 0, stream>>>(cnt, rowptr, N);
    k_fill<<<eb, 256, 0, stream>>>(row, col, deg, rowptr, pos, srcs, wsort, E);
    k_prop<<<N, 256, 0, stream>>>(x,  P1, rowptr, srcs, wsort, N);
    k_prop<<<N, 256, 0, stream>>>(P1, P2, rowptr, srcs, wsort, N);
    k_prepf<<<20, 256, 0, stream>>>(cheb_W, time_W, res_W, pBa, pBr, pBt);

    int items  = 2 * N;
    int blocks = (items + WPB - 1) / WPB;   // 4 waves/block, 1 item/wave
    k_fused<<<blocks, 64 * WPB, 0, stream>>>(x, P1, P2, pBa, pBr, pBt,
                                             cheb_b, time_b, res_b, ln_g, ln_b, out, N);
}